// Round 1
// baseline (558.677 us; speedup 1.0000x reference)
//
#include <hip/hip_runtime.h>
#include <hip/hip_bf16.h>
#include <math.h>

typedef __bf16 bf16_t;
typedef float f32x4 __attribute__((ext_vector_type(4)));
typedef bf16_t bf16x8 __attribute__((ext_vector_type(8)));

#define BM 128
#define BN 128
#define BKT 64
#define LDK 72   // 64 + 8 bf16 pad -> 144B row stride, 16B-aligned rows, ~2-way LDS banks

// ---------------- weight transpose + cast: dst[n][k] = (bf16)src[k][n], 512x512 ----------------
__global__ __launch_bounds__(256) void tcast_kernel(const float* __restrict__ src, bf16_t* __restrict__ dst) {
  int idx = blockIdx.x * 256 + threadIdx.x;   // 0 .. 512*512-1
  int n = idx >> 9, k = idx & 511;
  dst[idx] = (bf16_t)src[k * 512 + n];
}

// ---------------- KNN: one block per query point; exact fp32 dists, (dist,idx) lexicographic top-16 ----------------
__global__ __launch_bounds__(256) void knn_kernel(const float* __restrict__ xyz, int* __restrict__ knn) {
  __shared__ float sx[2048], sy[2048], sz[2048], sq[2048], dist[2048];
  __shared__ float wd[4];
  __shared__ int   wi[4];
  int tid = threadIdx.x;
  int gq = blockIdx.x;           // global query index = b*2048 + i
  int b  = gq >> 11;
  int base = b << 11;
  for (int p = tid; p < 2048; p += 256) {
    float x = xyz[(base + p) * 3 + 0];
    float y = xyz[(base + p) * 3 + 1];
    float z = xyz[(base + p) * 3 + 2];
    sx[p] = x; sy[p] = y; sz[p] = z;
    // sq = x*x + y*y + z*z, no FMA contraction (matches elementwise-square-then-sum)
    sq[p] = __fadd_rn(__fadd_rn(__fmul_rn(x, x), __fmul_rn(y, y)), __fmul_rn(z, z));
  }
  __syncthreads();
  int iq = gq & 2047;
  float qx = sx[iq], qy = sy[iq], qz = sz[iq], sqi = sq[iq];
  for (int p = tid; p < 2048; p += 256) {
    float d = __fmul_rn(sx[p], qx);
    d = fmaf(sy[p], qy, d);
    d = fmaf(sz[p], qz, d);
    dist[p] = __fsub_rn(__fadd_rn(sqi, sq[p]), __fmul_rn(2.0f, d));
  }
  __syncthreads();
  int lane = tid & 63, wave = tid >> 6;
  for (int s = 0; s < 16; ++s) {
    float bd = INFINITY; int bi = 1 << 30;
    for (int p = tid; p < 2048; p += 256) {
      float dv = dist[p];
      if (dv < bd || (dv == bd && p < bi)) { bd = dv; bi = p; }
    }
    #pragma unroll
    for (int off = 32; off > 0; off >>= 1) {
      float od = __shfl_xor(bd, off);
      int   oi = __shfl_xor(bi, off);
      if (od < bd || (od == bd && oi < bi)) { bd = od; bi = oi; }
    }
    if (lane == 0) { wd[wave] = bd; wi[wave] = bi; }
    __syncthreads();
    if (tid == 0) {
      float fd = wd[0]; int fi = wi[0];
      for (int u = 1; u < 4; ++u)
        if (wd[u] < fd || (wd[u] == fd && wi[u] < fi)) { fd = wd[u]; fi = wi[u]; }
      knn[gq * 16 + s] = base + fi;   // store GLOBAL point index
      dist[fi] = INFINITY;
    }
    __syncthreads();
  }
}

// ---------------- x = points @ fc1_w + fc1_b -> bf16 [4096][512] ----------------
__global__ __launch_bounds__(256) void xfeat_kernel(const float* __restrict__ points, const float* __restrict__ fc1_w,
                                                    const float* __restrict__ fc1_b, bf16_t* __restrict__ xb) {
  __shared__ float p[32];
  int m = blockIdx.x, tid = threadIdx.x;
  if (tid < 32) p[tid] = points[m * 32 + tid];
  __syncthreads();
  for (int c = tid; c < 512; c += 256) {
    float a = fc1_b[c];
    #pragma unroll
    for (int kk = 0; kk < 32; ++kk) a = fmaf(p[kk], fc1_w[kk * 512 + c], a);
    xb[m * 512 + c] = (bf16_t)a;
  }
}

// ---------------- h1 = relu(delta @ delta_w1 + delta_b1) -> bf16 [65536][512]; one block per group g ----------------
__global__ __launch_bounds__(256) void h1_kernel(const float* __restrict__ xyz, const int* __restrict__ knn,
                                                 const float* __restrict__ dw1, const float* __restrict__ db1,
                                                 bf16_t* __restrict__ h1) {
  __shared__ float w0[512], w1r[512], w2[512], bb[512];
  int g = blockIdx.x, tid = threadIdx.x;
  for (int c = tid; c < 512; c += 256) {
    w0[c] = dw1[c]; w1r[c] = dw1[512 + c]; w2[c] = dw1[1024 + c]; bb[c] = db1[c];
  }
  float xi0 = xyz[g * 3 + 0], xi1 = xyz[g * 3 + 1], xi2 = xyz[g * 3 + 2];
  __syncthreads();
  for (int slot = 0; slot < 16; ++slot) {
    int j = knn[g * 16 + slot];  // global
    float d0 = xi0 - xyz[j * 3 + 0];
    float d1 = xi1 - xyz[j * 3 + 1];
    float d2 = xi2 - xyz[j * 3 + 2];
    int m = g * 16 + slot;
    for (int c = tid; c < 512; c += 256) {
      float h = fmaf(d2, w2[c], fmaf(d1, w1r[c], d0 * w0[c])) + bb[c];
      h1[m * 512 + c] = (bf16_t)fmaxf(h, 0.0f);
    }
  }
}

// ---------------- res = res_mid @ fc2_w + fc2_b + points -> d_out[0:131072] ----------------
__global__ __launch_bounds__(256) void final_kernel(const float* __restrict__ res_mid, const float* __restrict__ fc2_w,
                                                    const float* __restrict__ fc2_b, const float* __restrict__ points,
                                                    float* __restrict__ out) {
  int oid = blockIdx.x * 256 + threadIdx.x;   // 0..131071
  int m = oid >> 5, c = oid & 31;
  float a = fc2_b[c];
  const float* rm = res_mid + m * 512;
  for (int kk = 0; kk < 512; ++kk) a = fmaf(rm[kk], fc2_w[kk * 32 + c], a);
  out[oid] = a + points[oid];
}

// ---------------- shared MFMA GEMM: C[M,N] = A[M,512] @ Bt[N,512]^T ----------------
// SRC: 0 = A from global bf16; 1 = gather prologue a_in = q - k_gathered + pe (f32) -> bf16
// EPI: 0 = f32 store (qkv); 1 = +bias f32 store (pe); 2 = relu(+bias) bf16 (h2);
//      3 = +bias, /sqrt(512), softmax over 16-row groups -> attn (overwrites pe in-place) + res_mid partials
template <int SRC, int EPI>
__global__ __launch_bounds__(256) void gemm_kernel(
    const bf16_t* __restrict__ A, const bf16_t* __restrict__ Bt,
    float* __restrict__ Cf, bf16_t* __restrict__ Cb,
    const float* __restrict__ bias, int ldc,
    const float* __restrict__ qkv, float* pe_attn,
    const int* __restrict__ knn, float* __restrict__ res_mid)
{
  __shared__ bf16_t Alds[BM][LDK];
  __shared__ bf16_t Blds[BN][LDK];
  int tid  = threadIdx.x;
  int lane = tid & 63, wave = tid >> 6;
  int wr = wave >> 1, wc = wave & 1;
  int lr = lane & 15, lg = lane >> 4;
  int n0 = blockIdx.x * BN, m0 = blockIdx.y * BM;

  f32x4 acc[4][4];
  #pragma unroll
  for (int i = 0; i < 4; ++i)
    #pragma unroll
    for (int j = 0; j < 4; ++j) acc[i][j] = (f32x4){0.f, 0.f, 0.f, 0.f};

  int srow = tid >> 3;         // 0..31
  int sc8  = (tid & 7) * 8;    // 0..56

  for (int k0 = 0; k0 < 512; k0 += BKT) {
    #pragma unroll
    for (int it = 0; it < 4; ++it) {
      int r = srow + it * 32;
      if (SRC == 0) {
        bf16x8 v = *(const bf16x8*)(A + (size_t)(m0 + r) * 512 + k0 + sc8);
        *(bf16x8*)(&Alds[r][sc8]) = v;
      } else {
        int m = m0 + r;
        int g = m >> 4;
        int j = knn[m];
        const float* qp = qkv + (size_t)g * 1536 + k0 + sc8;
        const float* kp = qkv + (size_t)j * 1536 + 512 + k0 + sc8;
        const float* pp = pe_attn + (size_t)m * 512 + k0 + sc8;
        f32x4 q0 = *(const f32x4*)qp,       q1 = *(const f32x4*)(qp + 4);
        f32x4 k0v = *(const f32x4*)kp,      k1v = *(const f32x4*)(kp + 4);
        f32x4 p0 = *(const f32x4*)pp,       p1 = *(const f32x4*)(pp + 4);
        bf16x8 o;
        #pragma unroll
        for (int u = 0; u < 4; ++u) o[u] = (bf16_t)(q0[u] - k0v[u] + p0[u]);
        #pragma unroll
        for (int u = 0; u < 4; ++u) o[4 + u] = (bf16_t)(q1[u] - k1v[u] + p1[u]);
        *(bf16x8*)(&Alds[r][sc8]) = o;
      }
      bf16x8 vb = *(const bf16x8*)(Bt + (size_t)(n0 + r) * 512 + k0 + sc8);
      *(bf16x8*)(&Blds[r][sc8]) = vb;
    }
    __syncthreads();
    #pragma unroll
    for (int kk = 0; kk < BKT; kk += 32) {
      int ko = kk + 8 * lg;
      bf16x8 af[4], bfr[4];
      #pragma unroll
      for (int mi = 0; mi < 4; ++mi) af[mi] = *(const bf16x8*)(&Alds[wr * 64 + mi * 16 + lr][ko]);
      #pragma unroll
      for (int nj = 0; nj < 4; ++nj) bfr[nj] = *(const bf16x8*)(&Blds[wc * 64 + nj * 16 + lr][ko]);
      #pragma unroll
      for (int mi = 0; mi < 4; ++mi)
        #pragma unroll
        for (int nj = 0; nj < 4; ++nj)
          acc[mi][nj] = __builtin_amdgcn_mfma_f32_16x16x32_bf16(af[mi], bfr[nj], acc[mi][nj], 0, 0, 0);
    }
    __syncthreads();
  }

  if (EPI == 0 || EPI == 1) {
    #pragma unroll
    for (int mi = 0; mi < 4; ++mi)
      #pragma unroll
      for (int nj = 0; nj < 4; ++nj) {
        int col = n0 + wc * 64 + nj * 16 + lr;
        #pragma unroll
        for (int r = 0; r < 4; ++r) {
          int row = m0 + wr * 64 + mi * 16 + lg * 4 + r;
          float v = acc[mi][nj][r];
          if (EPI == 1) v += bias[col];
          Cf[(size_t)row * ldc + col] = v;
        }
      }
  } else if (EPI == 2) {
    #pragma unroll
    for (int mi = 0; mi < 4; ++mi)
      #pragma unroll
      for (int nj = 0; nj < 4; ++nj) {
        int col = n0 + wc * 64 + nj * 16 + lr;
        #pragma unroll
        for (int r = 0; r < 4; ++r) {
          int row = m0 + wr * 64 + mi * 16 + lg * 4 + r;
          Cb[(size_t)row * ldc + col] = (bf16_t)fmaxf(acc[mi][nj][r] + bias[col], 0.0f);
        }
      }
  } else {
    // softmax over neighbors: each 16x16 MFMA acc tile covers exactly one group of 16 k-slots
    const float scale = 22.62741699796952f;   // float(np.sqrt(512))
    #pragma unroll
    for (int mi = 0; mi < 4; ++mi) {
      int g = (m0 + wr * 64 + mi * 16) >> 4;
      #pragma unroll
      for (int nj = 0; nj < 4; ++nj) {
        int col = n0 + wc * 64 + nj * 16 + lr;
        float sv[4];
        float mx = -INFINITY;
        #pragma unroll
        for (int r = 0; r < 4; ++r) {
          sv[r] = (acc[mi][nj][r] + bias[col]) / scale;
          mx = fmaxf(mx, sv[r]);
        }
        mx = fmaxf(mx, __shfl_xor(mx, 16));
        mx = fmaxf(mx, __shfl_xor(mx, 32));
        float e[4], sum = 0.f;
        #pragma unroll
        for (int r = 0; r < 4; ++r) { e[r] = expf(sv[r] - mx); sum += e[r]; }
        sum += __shfl_xor(sum, 16);
        sum += __shfl_xor(sum, 32);
        float part = 0.f;
        #pragma unroll
        for (int r = 0; r < 4; ++r) {
          int row = g * 16 + lg * 4 + r;
          float at = e[r] / sum;
          int j = knn[row];                                  // global point index of this slot
          float vv  = qkv[(size_t)j * 1536 + 1024 + col];    // v
          float pev = pe_attn[(size_t)row * 512 + col];      // read pe BEFORE overwriting with attn (same lane)
          part = fmaf(at, vv + pev, part);
          pe_attn[(size_t)row * 512 + col] = at;
        }
        part += __shfl_xor(part, 16);
        part += __shfl_xor(part, 32);
        if (lg == 0) res_mid[(size_t)g * 512 + col] = part;
      }
    }
  }
}

extern "C" void kernel_launch(void* const* d_in, const int* in_sizes, int n_in,
                              void* d_out, int out_size, void* d_ws, size_t ws_size,
                              hipStream_t stream) {
  const float* xyz    = (const float*)d_in[0];
  const float* points = (const float*)d_in[1];
  const float* fc1_w  = (const float*)d_in[2];
  const float* fc1_b  = (const float*)d_in[3];
  const float* fc2_w  = (const float*)d_in[4];
  const float* fc2_b  = (const float*)d_in[5];
  const float* dw1    = (const float*)d_in[6];
  const float* db1    = (const float*)d_in[7];
  const float* dw2    = (const float*)d_in[8];
  const float* db2    = (const float*)d_in[9];
  const float* gw1    = (const float*)d_in[10];
  const float* gb1    = (const float*)d_in[11];
  const float* gw2    = (const float*)d_in[12];
  const float* gb2    = (const float*)d_in[13];
  const float* wq     = (const float*)d_in[14];
  const float* wk     = (const float*)d_in[15];
  const float* wv     = (const float*)d_in[16];

  float* out = (float*)d_out;
  float* attn_pe = out + 131072;   // [65536][512] f32: holds pos_enc, overwritten in-place by attn

  char* w = (char*)d_ws;
  bf16_t* wqkvT  = (bf16_t*)w; w += (size_t)1536 * 512 * 2;
  bf16_t* dw2T   = (bf16_t*)w; w += (size_t)512 * 512 * 2;
  bf16_t* gw1T   = (bf16_t*)w; w += (size_t)512 * 512 * 2;
  bf16_t* gw2T   = (bf16_t*)w; w += (size_t)512 * 512 * 2;
  int*    knn    = (int*)w;    w += (size_t)65536 * 4;
  bf16_t* xb     = (bf16_t*)w; w += (size_t)4096 * 512 * 2;
  float*  qkv    = (float*)w;  w += (size_t)4096 * 1536 * 4;
  bf16_t* h12    = (bf16_t*)w; w += (size_t)65536 * 512 * 2;   // h1, then overwritten by h2
  float*  res_mid= (float*)w;  w += (size_t)4096 * 512 * 4;
  // total ws: ~104 MB

  tcast_kernel<<<1024, 256, 0, stream>>>(wq,  wqkvT);
  tcast_kernel<<<1024, 256, 0, stream>>>(wk,  wqkvT + 512 * 512);
  tcast_kernel<<<1024, 256, 0, stream>>>(wv,  wqkvT + 2 * 512 * 512);
  tcast_kernel<<<1024, 256, 0, stream>>>(dw2, dw2T);
  tcast_kernel<<<1024, 256, 0, stream>>>(gw1, gw1T);
  tcast_kernel<<<1024, 256, 0, stream>>>(gw2, gw2T);

  knn_kernel<<<4096, 256, 0, stream>>>(xyz, knn);
  xfeat_kernel<<<4096, 256, 0, stream>>>(points, fc1_w, fc1_b, xb);

  // qkv = x @ [wq|wk|wv]  -> f32 [4096][1536]
  gemm_kernel<0, 0><<<dim3(12, 32), 256, 0, stream>>>(xb, wqkvT, qkv, nullptr, nullptr, 1536,
                                                      nullptr, nullptr, nullptr, nullptr);
  h1_kernel<<<4096, 256, 0, stream>>>(xyz, knn, dw1, db1, h12);

  // pos_enc = h1 @ delta_w2 + delta_b2 -> f32 into attn region of d_out
  gemm_kernel<0, 1><<<dim3(4, 512), 256, 0, stream>>>(h12, dw2T, attn_pe, nullptr, db2, 512,
                                                      nullptr, nullptr, nullptr, nullptr);

  // h2 = relu((q - k_gathered + pos_enc) @ gamma_w1 + gamma_b1) -> bf16 (overwrites h1)
  gemm_kernel<1, 2><<<dim3(4, 512), 256, 0, stream>>>(nullptr, gw1T, nullptr, h12, gb1, 512,
                                                      qkv, attn_pe, knn, nullptr);

  // a = h2 @ gamma_w2 + gamma_b2; attn = softmax(a/sqrt(512)) over k; res_mid = sum_k attn*(v+pe)
  gemm_kernel<0, 3><<<dim3(4, 512), 256, 0, stream>>>(h12, gw2T, nullptr, nullptr, gb2, 512,
                                                      qkv, attn_pe, knn, res_mid);

  final_kernel<<<512, 256, 0, stream>>>(res_mid, fc2_w, fc2_b, points, out);
}

// Round 2
// 468.069 us; speedup vs baseline: 1.1936x; 1.1936x over previous
//
#include <hip/hip_runtime.h>
#include <hip/hip_bf16.h>
#include <math.h>

typedef __bf16 bf16_t;
typedef float f32x4 __attribute__((ext_vector_type(4)));
typedef bf16_t bf16x8 __attribute__((ext_vector_type(8)));

#define BM 128
#define BN 128
#define BKT 64
#define LDK 72   // 64 + 8 bf16 pad

// ---------------- fused weight transpose + cast: 6 x (dst[n][k] = (bf16)src[k][n], 512x512) ----------------
struct TC6 { const float* src[6]; bf16_t* dst[6]; };
__global__ __launch_bounds__(256) void tcast6_kernel(TC6 tc) {
  int job = blockIdx.x >> 10;                       // 1024 blocks per 512x512 matrix
  int idx = (blockIdx.x & 1023) * 256 + threadIdx.x;
  int n = idx >> 9, k = idx & 511;
  tc.dst[job][idx] = (bf16_t)tc.src[job][k * 512 + n];
}

// ---------------- KNN: one WAVE per query; per-lane u64 keys in registers, no barriers in selection ----------------
// key = (sortable_float(dist) << 32) | point_idx  ->  u64 min == lexicographic (dist, idx) min == top_k tie-break
__global__ __launch_bounds__(256) void knn_kernel(const float* __restrict__ xyz, int* __restrict__ knn) {
  __shared__ float sx[2048], sy[2048], sz[2048], sq[2048];
  int tid = threadIdx.x;
  int lane = tid & 63, wave = tid >> 6;
  int gq = blockIdx.x * 4 + wave;        // 4 queries per block, one per wave
  int b  = gq >> 11;
  int base = b << 11;
  for (int p = tid; p < 2048; p += 256) {
    float x = xyz[(base + p) * 3 + 0];
    float y = xyz[(base + p) * 3 + 1];
    float z = xyz[(base + p) * 3 + 2];
    sx[p] = x; sy[p] = y; sz[p] = z;
    // identical rounding to reference: elementwise square, then sum (no FMA contraction)
    sq[p] = __fadd_rn(__fadd_rn(__fmul_rn(x, x), __fmul_rn(y, y)), __fmul_rn(z, z));
  }
  __syncthreads();
  int iq = gq & 2047;
  float qx = sx[iq], qy = sy[iq], qz = sz[iq], sqi = sq[iq];

  unsigned long long key[32];
  #pragma unroll
  for (int j = 0; j < 32; ++j) {
    int p = lane + j * 64;
    float d = __fmul_rn(sx[p], qx);
    d = fmaf(sy[p], qy, d);
    d = fmaf(sz[p], qz, d);
    float dist = __fsub_rn(__fadd_rn(sqi, sq[p]), __fmul_rn(2.0f, d));
    unsigned int bits = __float_as_uint(dist);
    unsigned int sk = bits ^ (unsigned int)(((int)bits >> 31) | 0x80000000);  // monotone float->uint
    key[j] = ((unsigned long long)sk << 32) | (unsigned int)p;
  }

  int r = 0;
  #pragma unroll 1
  for (int s = 0; s < 16; ++s) {
    unsigned long long m = key[0];
    #pragma unroll
    for (int j = 1; j < 32; ++j) m = (key[j] < m) ? key[j] : m;
    #pragma unroll
    for (int off = 32; off > 0; off >>= 1) {
      unsigned long long o = (unsigned long long)__shfl_xor((long long)m, off);
      if (o < m) m = o;
    }
    if (lane == s) r = base + (int)(m & 0xFFFFFFFFu);
    #pragma unroll
    for (int j = 0; j < 32; ++j) key[j] = (key[j] == m) ? ~0ULL : key[j];
  }
  if (lane < 16) knn[gq * 16 + lane] = r;
}

// ---------------- x = points @ fc1_w + fc1_b -> bf16 [4096][512] ----------------
__global__ __launch_bounds__(256) void xfeat_kernel(const float* __restrict__ points, const float* __restrict__ fc1_w,
                                                    const float* __restrict__ fc1_b, bf16_t* __restrict__ xb) {
  __shared__ float p[32];
  int m = blockIdx.x, tid = threadIdx.x;
  if (tid < 32) p[tid] = points[m * 32 + tid];
  __syncthreads();
  for (int c = tid; c < 512; c += 256) {
    float a = fc1_b[c];
    #pragma unroll
    for (int kk = 0; kk < 32; ++kk) a = fmaf(p[kk], fc1_w[kk * 512 + c], a);
    xb[m * 512 + c] = (bf16_t)a;
  }
}

// ---------------- h1 = relu(delta @ delta_w1 + delta_b1) -> bf16 [65536][512] ----------------
__global__ __launch_bounds__(256) void h1_kernel(const float* __restrict__ xyz, const int* __restrict__ knn,
                                                 const float* __restrict__ dw1, const float* __restrict__ db1,
                                                 bf16_t* __restrict__ h1) {
  __shared__ float w0[512], w1r[512], w2[512], bb[512];
  int g = blockIdx.x, tid = threadIdx.x;
  for (int c = tid; c < 512; c += 256) {
    w0[c] = dw1[c]; w1r[c] = dw1[512 + c]; w2[c] = dw1[1024 + c]; bb[c] = db1[c];
  }
  float xi0 = xyz[g * 3 + 0], xi1 = xyz[g * 3 + 1], xi2 = xyz[g * 3 + 2];
  __syncthreads();
  for (int slot = 0; slot < 16; ++slot) {
    int j = knn[g * 16 + slot];  // global
    float d0 = xi0 - xyz[j * 3 + 0];
    float d1 = xi1 - xyz[j * 3 + 1];
    float d2 = xi2 - xyz[j * 3 + 2];
    int m = g * 16 + slot;
    for (int c = tid; c < 512; c += 256) {
      float h = fmaf(d2, w2[c], fmaf(d1, w1r[c], d0 * w0[c])) + bb[c];
      h1[m * 512 + c] = (bf16_t)fmaxf(h, 0.0f);
    }
  }
}

// ---------------- res = res_mid @ fc2_w + fc2_b + points -> d_out[0:131072] ----------------
__global__ __launch_bounds__(256) void final_kernel(const float* __restrict__ res_mid, const float* __restrict__ fc2_w,
                                                    const float* __restrict__ fc2_b, const float* __restrict__ points,
                                                    float* __restrict__ out) {
  int oid = blockIdx.x * 256 + threadIdx.x;   // 0..131071
  int m = oid >> 5, c = oid & 31;
  float a = fc2_b[c];
  const float* rm = res_mid + m * 512;
  for (int kk = 0; kk < 512; ++kk) a = fmaf(rm[kk], fc2_w[kk * 32 + c], a);
  out[oid] = a + points[oid];
}

// ---------------- shared MFMA GEMM: C[M,N] = A[M,512] @ Bt[N,512]^T ----------------
// SRC: 0 = A from global bf16; 1 = gather prologue a_in = q - k_gathered + pe (f32) -> bf16
// EPI: 0 = f32 store (qkv); 1 = +bias f32 store (pe); 2 = relu(+bias) bf16 (h2);
//      3 = +bias, /sqrt(512), softmax over 16-row groups -> attn (overwrites pe in-place) + res_mid partials
template <int SRC, int EPI>
__global__ __launch_bounds__(256) void gemm_kernel(
    const bf16_t* __restrict__ A, const bf16_t* __restrict__ Bt,
    float* __restrict__ Cf, bf16_t* __restrict__ Cb,
    const float* __restrict__ bias, int ldc,
    const float* __restrict__ qkv, float* pe_attn,
    const int* __restrict__ knn, float* __restrict__ res_mid)
{
  __shared__ bf16_t Alds[BM][LDK];
  __shared__ bf16_t Blds[BN][LDK];
  int tid  = threadIdx.x;
  int lane = tid & 63, wave = tid >> 6;
  int wr = wave >> 1, wc = wave & 1;
  int lr = lane & 15, lg = lane >> 4;
  int n0 = blockIdx.x * BN, m0 = blockIdx.y * BM;

  f32x4 acc[4][4];
  #pragma unroll
  for (int i = 0; i < 4; ++i)
    #pragma unroll
    for (int j = 0; j < 4; ++j) acc[i][j] = (f32x4){0.f, 0.f, 0.f, 0.f};

  int srow = tid >> 3;         // 0..31
  int sc8  = (tid & 7) * 8;    // 0..56

  for (int k0 = 0; k0 < 512; k0 += BKT) {
    #pragma unroll
    for (int it = 0; it < 4; ++it) {
      int r = srow + it * 32;
      if (SRC == 0) {
        bf16x8 v = *(const bf16x8*)(A + (size_t)(m0 + r) * 512 + k0 + sc8);
        *(bf16x8*)(&Alds[r][sc8]) = v;
      } else {
        int m = m0 + r;
        int g = m >> 4;
        int j = knn[m];
        const float* qp = qkv + (size_t)g * 1536 + k0 + sc8;
        const float* kp = qkv + (size_t)j * 1536 + 512 + k0 + sc8;
        const float* pp = pe_attn + (size_t)m * 512 + k0 + sc8;
        f32x4 q0 = *(const f32x4*)qp,       q1 = *(const f32x4*)(qp + 4);
        f32x4 k0v = *(const f32x4*)kp,      k1v = *(const f32x4*)(kp + 4);
        f32x4 p0 = *(const f32x4*)pp,       p1 = *(const f32x4*)(pp + 4);
        bf16x8 o;
        #pragma unroll
        for (int u = 0; u < 4; ++u) o[u] = (bf16_t)(q0[u] - k0v[u] + p0[u]);
        #pragma unroll
        for (int u = 0; u < 4; ++u) o[4 + u] = (bf16_t)(q1[u] - k1v[u] + p1[u]);
        *(bf16x8*)(&Alds[r][sc8]) = o;
      }
      bf16x8 vb = *(const bf16x8*)(Bt + (size_t)(n0 + r) * 512 + k0 + sc8);
      *(bf16x8*)(&Blds[r][sc8]) = vb;
    }
    __syncthreads();
    #pragma unroll
    for (int kk = 0; kk < BKT; kk += 32) {
      int ko = kk + 8 * lg;
      bf16x8 af[4], bfr[4];
      #pragma unroll
      for (int mi = 0; mi < 4; ++mi) af[mi] = *(const bf16x8*)(&Alds[wr * 64 + mi * 16 + lr][ko]);
      #pragma unroll
      for (int nj = 0; nj < 4; ++nj) bfr[nj] = *(const bf16x8*)(&Blds[wc * 64 + nj * 16 + lr][ko]);
      #pragma unroll
      for (int mi = 0; mi < 4; ++mi)
        #pragma unroll
        for (int nj = 0; nj < 4; ++nj)
          acc[mi][nj] = __builtin_amdgcn_mfma_f32_16x16x32_bf16(af[mi], bfr[nj], acc[mi][nj], 0, 0, 0);
    }
    __syncthreads();
  }

  if (EPI == 0 || EPI == 1) {
    #pragma unroll
    for (int mi = 0; mi < 4; ++mi)
      #pragma unroll
      for (int nj = 0; nj < 4; ++nj) {
        int col = n0 + wc * 64 + nj * 16 + lr;
        #pragma unroll
        for (int r = 0; r < 4; ++r) {
          int row = m0 + wr * 64 + mi * 16 + lg * 4 + r;
          float v = acc[mi][nj][r];
          if (EPI == 1) v += bias[col];
          Cf[(size_t)row * ldc + col] = v;
        }
      }
  } else if (EPI == 2) {
    #pragma unroll
    for (int mi = 0; mi < 4; ++mi)
      #pragma unroll
      for (int nj = 0; nj < 4; ++nj) {
        int col = n0 + wc * 64 + nj * 16 + lr;
        #pragma unroll
        for (int r = 0; r < 4; ++r) {
          int row = m0 + wr * 64 + mi * 16 + lg * 4 + r;
          Cb[(size_t)row * ldc + col] = (bf16_t)fmaxf(acc[mi][nj][r] + bias[col], 0.0f);
        }
      }
  } else {
    // softmax over neighbors: each 16x16 MFMA acc tile covers exactly one group of 16 k-slots
    const float scale = 22.62741699796952f;   // float(np.sqrt(512))
    #pragma unroll
    for (int mi = 0; mi < 4; ++mi) {
      int g = (m0 + wr * 64 + mi * 16) >> 4;
      #pragma unroll
      for (int nj = 0; nj < 4; ++nj) {
        int col = n0 + wc * 64 + nj * 16 + lr;
        float sv[4];
        float mx = -INFINITY;
        #pragma unroll
        for (int r = 0; r < 4; ++r) {
          sv[r] = (acc[mi][nj][r] + bias[col]) / scale;
          mx = fmaxf(mx, sv[r]);
        }
        mx = fmaxf(mx, __shfl_xor(mx, 16));
        mx = fmaxf(mx, __shfl_xor(mx, 32));
        float e[4], sum = 0.f;
        #pragma unroll
        for (int r = 0; r < 4; ++r) { e[r] = expf(sv[r] - mx); sum += e[r]; }
        sum += __shfl_xor(sum, 16);
        sum += __shfl_xor(sum, 32);
        float part = 0.f;
        #pragma unroll
        for (int r = 0; r < 4; ++r) {
          int row = g * 16 + lg * 4 + r;
          float at = e[r] / sum;
          int j = knn[row];                                  // global point index of this slot
          float vv  = qkv[(size_t)j * 1536 + 1024 + col];    // v
          float pev = pe_attn[(size_t)row * 512 + col];      // read pe BEFORE overwriting with attn (same lane)
          part = fmaf(at, vv + pev, part);
          pe_attn[(size_t)row * 512 + col] = at;
        }
        part += __shfl_xor(part, 16);
        part += __shfl_xor(part, 32);
        if (lg == 0) res_mid[(size_t)g * 512 + col] = part;
      }
    }
  }
}

extern "C" void kernel_launch(void* const* d_in, const int* in_sizes, int n_in,
                              void* d_out, int out_size, void* d_ws, size_t ws_size,
                              hipStream_t stream) {
  const float* xyz    = (const float*)d_in[0];
  const float* points = (const float*)d_in[1];
  const float* fc1_w  = (const float*)d_in[2];
  const float* fc1_b  = (const float*)d_in[3];
  const float* fc2_w  = (const float*)d_in[4];
  const float* fc2_b  = (const float*)d_in[5];
  const float* dw1    = (const float*)d_in[6];
  const float* db1    = (const float*)d_in[7];
  const float* dw2    = (const float*)d_in[8];
  const float* db2    = (const float*)d_in[9];
  const float* gw1    = (const float*)d_in[10];
  const float* gb1    = (const float*)d_in[11];
  const float* gw2    = (const float*)d_in[12];
  const float* gb2    = (const float*)d_in[13];
  const float* wq     = (const float*)d_in[14];
  const float* wk     = (const float*)d_in[15];
  const float* wv     = (const float*)d_in[16];

  float* out = (float*)d_out;
  float* attn_pe = out + 131072;   // [65536][512] f32: holds pos_enc, overwritten in-place by attn

  char* w = (char*)d_ws;
  bf16_t* wqkvT  = (bf16_t*)w; w += (size_t)1536 * 512 * 2;
  bf16_t* dw2T   = (bf16_t*)w; w += (size_t)512 * 512 * 2;
  bf16_t* gw1T   = (bf16_t*)w; w += (size_t)512 * 512 * 2;
  bf16_t* gw2T   = (bf16_t*)w; w += (size_t)512 * 512 * 2;
  int*    knn    = (int*)w;    w += (size_t)65536 * 4;
  bf16_t* xb     = (bf16_t*)w; w += (size_t)4096 * 512 * 2;
  float*  qkv    = (float*)w;  w += (size_t)4096 * 1536 * 4;
  bf16_t* h12    = (bf16_t*)w; w += (size_t)65536 * 512 * 2;   // h1, then overwritten by h2
  float*  res_mid= (float*)w;  w += (size_t)4096 * 512 * 4;

  TC6 tc;
  tc.src[0] = wq;  tc.dst[0] = wqkvT;
  tc.src[1] = wk;  tc.dst[1] = wqkvT + 512 * 512;
  tc.src[2] = wv;  tc.dst[2] = wqkvT + 2 * 512 * 512;
  tc.src[3] = dw2; tc.dst[3] = dw2T;
  tc.src[4] = gw1; tc.dst[4] = gw1T;
  tc.src[5] = gw2; tc.dst[5] = gw2T;
  tcast6_kernel<<<6144, 256, 0, stream>>>(tc);

  knn_kernel<<<1024, 256, 0, stream>>>(xyz, knn);
  xfeat_kernel<<<4096, 256, 0, stream>>>(points, fc1_w, fc1_b, xb);

  // qkv = x @ [wq|wk|wv]  -> f32 [4096][1536]
  gemm_kernel<0, 0><<<dim3(12, 32), 256, 0, stream>>>(xb, wqkvT, qkv, nullptr, nullptr, 1536,
                                                      nullptr, nullptr, nullptr, nullptr);
  h1_kernel<<<4096, 256, 0, stream>>>(xyz, knn, dw1, db1, h12);

  // pos_enc = h1 @ delta_w2 + delta_b2 -> f32 into attn region of d_out
  gemm_kernel<0, 1><<<dim3(4, 512), 256, 0, stream>>>(h12, dw2T, attn_pe, nullptr, db2, 512,
                                                      nullptr, nullptr, nullptr, nullptr);

  // h2 = relu((q - k_gathered + pos_enc) @ gamma_w1 + gamma_b1) -> bf16 (overwrites h1)
  gemm_kernel<1, 2><<<dim3(4, 512), 256, 0, stream>>>(nullptr, gw1T, nullptr, h12, gb1, 512,
                                                      qkv, attn_pe, knn, nullptr);

  // a = h2 @ gamma_w2 + gamma_b2; attn = softmax(a/sqrt(512)) over k; res_mid = sum_k attn*(v+pe)
  gemm_kernel<0, 3><<<dim3(4, 512), 256, 0, stream>>>(h12, gw2T, nullptr, nullptr, gb2, 512,
                                                      qkv, attn_pe, knn, res_mid);

  final_kernel<<<512, 256, 0, stream>>>(res_mid, fc2_w, fc2_b, points, out);
}

// Round 3
// 432.853 us; speedup vs baseline: 1.2907x; 1.0814x over previous
//
#include <hip/hip_runtime.h>
#include <hip/hip_bf16.h>
#include <math.h>

typedef __bf16 bf16_t;
typedef float f32x4 __attribute__((ext_vector_type(4)));
typedef bf16_t bf16x8 __attribute__((ext_vector_type(8)));

#define BM 128
#define BN 128
#define BKT 64

// async global->LDS, 16B per lane; LDS dest = wave-uniform base + lane*16 (linear)
#define GLD_LDS16(gp, lp) __builtin_amdgcn_global_load_lds( \
    (const __attribute__((address_space(1))) void*)(gp), \
    (__attribute__((address_space(3))) void*)(lp), 16, 0, 0)

// ---------------- fused weight transpose + cast: 6 x (dst[n][k] = (bf16)src[k][n], 512x512) ----------------
struct TC6 { const float* src[6]; bf16_t* dst[6]; };
__global__ __launch_bounds__(256) void tcast6_kernel(TC6 tc) {
  int job = blockIdx.x >> 10;
  int idx = (blockIdx.x & 1023) * 256 + threadIdx.x;
  int n = idx >> 9, k = idx & 511;
  tc.dst[job][idx] = (bf16_t)tc.src[job][k * 512 + n];
}

// ---------------- KNN: one WAVE per query; per-lane u64 keys in registers ----------------
__global__ __launch_bounds__(256) void knn_kernel(const float* __restrict__ xyz, int* __restrict__ knn) {
  __shared__ float sx[2048], sy[2048], sz[2048], sq[2048];
  int tid = threadIdx.x;
  int lane = tid & 63, wave = tid >> 6;
  int gq = blockIdx.x * 4 + wave;
  int b  = gq >> 11;
  int base = b << 11;
  for (int p = tid; p < 2048; p += 256) {
    float x = xyz[(base + p) * 3 + 0];
    float y = xyz[(base + p) * 3 + 1];
    float z = xyz[(base + p) * 3 + 2];
    sx[p] = x; sy[p] = y; sz[p] = z;
    sq[p] = __fadd_rn(__fadd_rn(__fmul_rn(x, x), __fmul_rn(y, y)), __fmul_rn(z, z));
  }
  __syncthreads();
  int iq = gq & 2047;
  float qx = sx[iq], qy = sy[iq], qz = sz[iq], sqi = sq[iq];

  unsigned long long key[32];
  #pragma unroll
  for (int j = 0; j < 32; ++j) {
    int p = lane + j * 64;
    float d = __fmul_rn(sx[p], qx);
    d = fmaf(sy[p], qy, d);
    d = fmaf(sz[p], qz, d);
    float dist = __fsub_rn(__fadd_rn(sqi, sq[p]), __fmul_rn(2.0f, d));
    unsigned int bits = __float_as_uint(dist);
    unsigned int sk = bits ^ (unsigned int)(((int)bits >> 31) | 0x80000000);
    key[j] = ((unsigned long long)sk << 32) | (unsigned int)p;
  }

  int r = 0;
  #pragma unroll 1
  for (int s = 0; s < 16; ++s) {
    unsigned long long m = key[0];
    #pragma unroll
    for (int j = 1; j < 32; ++j) m = (key[j] < m) ? key[j] : m;
    #pragma unroll
    for (int off = 32; off > 0; off >>= 1) {
      unsigned long long o = (unsigned long long)__shfl_xor((long long)m, off);
      if (o < m) m = o;
    }
    if (lane == s) r = base + (int)(m & 0xFFFFFFFFu);
    #pragma unroll
    for (int j = 0; j < 32; ++j) key[j] = (key[j] == m) ? ~0ULL : key[j];
  }
  if (lane < 16) knn[gq * 16 + lane] = r;
}

// ---------------- x = points @ fc1_w + fc1_b -> bf16 [4096][512] ----------------
__global__ __launch_bounds__(256) void xfeat_kernel(const float* __restrict__ points, const float* __restrict__ fc1_w,
                                                    const float* __restrict__ fc1_b, bf16_t* __restrict__ xb) {
  __shared__ float p[32];
  int m = blockIdx.x, tid = threadIdx.x;
  if (tid < 32) p[tid] = points[m * 32 + tid];
  __syncthreads();
  for (int c = tid; c < 512; c += 256) {
    float a = fc1_b[c];
    #pragma unroll
    for (int kk = 0; kk < 32; ++kk) a = fmaf(p[kk], fc1_w[kk * 512 + c], a);
    xb[m * 512 + c] = (bf16_t)a;
  }
}

// ---------------- h1 = relu(delta @ delta_w1 + delta_b1) -> bf16 [65536][512] ----------------
__global__ __launch_bounds__(256) void h1_kernel(const float* __restrict__ xyz, const int* __restrict__ knn,
                                                 const float* __restrict__ dw1, const float* __restrict__ db1,
                                                 bf16_t* __restrict__ h1) {
  __shared__ float w0[512], w1r[512], w2[512], bb[512];
  int g = blockIdx.x, tid = threadIdx.x;
  for (int c = tid; c < 512; c += 256) {
    w0[c] = dw1[c]; w1r[c] = dw1[512 + c]; w2[c] = dw1[1024 + c]; bb[c] = db1[c];
  }
  float xi0 = xyz[g * 3 + 0], xi1 = xyz[g * 3 + 1], xi2 = xyz[g * 3 + 2];
  __syncthreads();
  for (int slot = 0; slot < 16; ++slot) {
    int j = knn[g * 16 + slot];
    float d0 = xi0 - xyz[j * 3 + 0];
    float d1 = xi1 - xyz[j * 3 + 1];
    float d2 = xi2 - xyz[j * 3 + 2];
    int m = g * 16 + slot;
    for (int c = tid; c < 512; c += 256) {
      float h = fmaf(d2, w2[c], fmaf(d1, w1r[c], d0 * w0[c])) + bb[c];
      h1[m * 512 + c] = (bf16_t)fmaxf(h, 0.0f);
    }
  }
}

// ---------------- res = res_mid @ fc2_w + fc2_b + points -> d_out[0:131072] ----------------
__global__ __launch_bounds__(256) void final_kernel(const float* __restrict__ res_mid, const float* __restrict__ fc2_w,
                                                    const float* __restrict__ fc2_b, const float* __restrict__ points,
                                                    float* __restrict__ out) {
  int oid = blockIdx.x * 256 + threadIdx.x;
  int m = oid >> 5, c = oid & 31;
  float a = fc2_b[c];
  const float* rm = res_mid + m * 512;
  for (int kk = 0; kk < 512; ++kk) a = fmaf(rm[kk], fc2_w[kk * 32 + c], a);
  out[oid] = a + points[oid];
}

// ---------------- MFMA GEMM, m97 structure: global_load_lds staging, linear [128][64] LDS ----------------
// SRC: 0 = A from global bf16 (async); 1 = gather prologue a = q - k_gathered + pe -> bf16 (reg-staged)
// EPI: 0 = f32 store; 1 = +bias f32 store; 2 = relu(+bias) bf16; 3 = softmax over 16-row groups + res_mid
template <int SRC, int EPI>
__global__ __launch_bounds__(256) void gemm_kernel(
    const bf16_t* __restrict__ A, const bf16_t* __restrict__ Bt,
    float* __restrict__ Cf, bf16_t* __restrict__ Cb,
    const float* __restrict__ bias, int ldc,
    const float* __restrict__ qkv, float* pe_attn,
    const int* __restrict__ knn, float* __restrict__ res_mid)
{
  __shared__ bf16_t Alds[BM * BKT];
  __shared__ bf16_t Blds[BN * BKT];
  int tid  = threadIdx.x;
  int lane = tid & 63, wave = tid >> 6;
  int wr = wave >> 1, wc = wave & 1;
  int lr = lane & 15, lg = lane >> 4;

  // XCD-aware bijective swizzle: dispatch slot s -> XCD s%8; give each XCD a contiguous work chunk
  int gx = gridDim.x;
  int nwg = gx * gridDim.y;
  int orig = blockIdx.y * gx + blockIdx.x;
  int cpx = nwg >> 3;                       // nwg % 8 == 0 for all our launches
  int swz = (orig & 7) * cpx + (orig >> 3);
  int bx = swz % gx;                        // N-tile (fastest -> same-M blocks adjacent on one XCD)
  int by = swz / gx;                        // M-tile
  int n0 = bx * BN, m0 = by * BM;

  f32x4 acc[4][4];
  #pragma unroll
  for (int i = 0; i < 4; ++i)
    #pragma unroll
    for (int j = 0; j < 4; ++j) acc[i][j] = (f32x4){0.f, 0.f, 0.f, 0.f};

  int srow = tid >> 3;         // 0..31
  int sc8  = (tid & 7) * 8;    // 0..56

  for (int k0 = 0; k0 < 512; k0 += BKT) {
    if (SRC == 0) {
      #pragma unroll
      for (int it = 0; it < 4; ++it) {
        int r = it * 32 + srow;
        GLD_LDS16(A + (size_t)(m0 + r) * 512 + k0 + sc8, Alds + (it * 4 + wave) * 512);
      }
    } else {
      #pragma unroll
      for (int it = 0; it < 4; ++it) {
        int r = it * 32 + srow;
        int m = m0 + r;
        int g = m >> 4;
        int j = knn[m];
        const float* qp = qkv + (size_t)g * 1536 + k0 + sc8;
        const float* kp = qkv + (size_t)j * 1536 + 512 + k0 + sc8;
        const float* pp = pe_attn + (size_t)m * 512 + k0 + sc8;
        f32x4 q0 = *(const f32x4*)qp,  q1 = *(const f32x4*)(qp + 4);
        f32x4 k0v = *(const f32x4*)kp, k1v = *(const f32x4*)(kp + 4);
        f32x4 p0 = *(const f32x4*)pp,  p1 = *(const f32x4*)(pp + 4);
        bf16x8 o;
        #pragma unroll
        for (int u = 0; u < 4; ++u) o[u] = (bf16_t)(q0[u] - k0v[u] + p0[u]);
        #pragma unroll
        for (int u = 0; u < 4; ++u) o[4 + u] = (bf16_t)(q1[u] - k1v[u] + p1[u]);
        *(bf16x8*)(&Alds[r * BKT + sc8]) = o;
      }
    }
    #pragma unroll
    for (int it = 0; it < 4; ++it) {
      int r = it * 32 + srow;
      GLD_LDS16(Bt + (size_t)(n0 + r) * 512 + k0 + sc8, Blds + (it * 4 + wave) * 512);
    }
    __syncthreads();
    #pragma unroll
    for (int kk = 0; kk < BKT; kk += 32) {
      int ko = kk + 8 * lg;
      bf16x8 af[4], bfr[4];
      #pragma unroll
      for (int mi = 0; mi < 4; ++mi) af[mi] = *(const bf16x8*)(&Alds[(wr * 64 + mi * 16 + lr) * BKT + ko]);
      #pragma unroll
      for (int nj = 0; nj < 4; ++nj) bfr[nj] = *(const bf16x8*)(&Blds[(wc * 64 + nj * 16 + lr) * BKT + ko]);
      #pragma unroll
      for (int mi = 0; mi < 4; ++mi)
        #pragma unroll
        for (int nj = 0; nj < 4; ++nj)
          acc[mi][nj] = __builtin_amdgcn_mfma_f32_16x16x32_bf16(af[mi], bfr[nj], acc[mi][nj], 0, 0, 0);
    }
    __syncthreads();
  }

  if (EPI == 0 || EPI == 1) {
    #pragma unroll
    for (int mi = 0; mi < 4; ++mi)
      #pragma unroll
      for (int nj = 0; nj < 4; ++nj) {
        int col = n0 + wc * 64 + nj * 16 + lr;
        #pragma unroll
        for (int r = 0; r < 4; ++r) {
          int row = m0 + wr * 64 + mi * 16 + lg * 4 + r;
          float v = acc[mi][nj][r];
          if (EPI == 1) v += bias[col];
          Cf[(size_t)row * ldc + col] = v;
        }
      }
  } else if (EPI == 2) {
    #pragma unroll
    for (int mi = 0; mi < 4; ++mi)
      #pragma unroll
      for (int nj = 0; nj < 4; ++nj) {
        int col = n0 + wc * 64 + nj * 16 + lr;
        #pragma unroll
        for (int r = 0; r < 4; ++r) {
          int row = m0 + wr * 64 + mi * 16 + lg * 4 + r;
          Cb[(size_t)row * ldc + col] = (bf16_t)fmaxf(acc[mi][nj][r] + bias[col], 0.0f);
        }
      }
  } else {
    const float scale = 22.62741699796952f;   // float(np.sqrt(512))
    #pragma unroll
    for (int mi = 0; mi < 4; ++mi) {
      int g = (m0 + wr * 64 + mi * 16) >> 4;
      #pragma unroll
      for (int nj = 0; nj < 4; ++nj) {
        int col = n0 + wc * 64 + nj * 16 + lr;
        float sv[4];
        float mx = -INFINITY;
        #pragma unroll
        for (int r = 0; r < 4; ++r) {
          sv[r] = (acc[mi][nj][r] + bias[col]) / scale;
          mx = fmaxf(mx, sv[r]);
        }
        mx = fmaxf(mx, __shfl_xor(mx, 16));
        mx = fmaxf(mx, __shfl_xor(mx, 32));
        float e[4], sum = 0.f;
        #pragma unroll
        for (int r = 0; r < 4; ++r) { e[r] = expf(sv[r] - mx); sum += e[r]; }
        sum += __shfl_xor(sum, 16);
        sum += __shfl_xor(sum, 32);
        float part = 0.f;
        #pragma unroll
        for (int r = 0; r < 4; ++r) {
          int row = g * 16 + lg * 4 + r;
          float at = e[r] / sum;
          int j = knn[row];
          float vv  = qkv[(size_t)j * 1536 + 1024 + col];
          float pev = pe_attn[(size_t)row * 512 + col];   // read pe BEFORE overwriting (same lane)
          part = fmaf(at, vv + pev, part);
          pe_attn[(size_t)row * 512 + col] = at;
        }
        part += __shfl_xor(part, 16);
        part += __shfl_xor(part, 32);
        if (lg == 0) res_mid[(size_t)g * 512 + col] = part;
      }
    }
  }
}

extern "C" void kernel_launch(void* const* d_in, const int* in_sizes, int n_in,
                              void* d_out, int out_size, void* d_ws, size_t ws_size,
                              hipStream_t stream) {
  const float* xyz    = (const float*)d_in[0];
  const float* points = (const float*)d_in[1];
  const float* fc1_w  = (const float*)d_in[2];
  const float* fc1_b  = (const float*)d_in[3];
  const float* fc2_w  = (const float*)d_in[4];
  const float* fc2_b  = (const float*)d_in[5];
  const float* dw1    = (const float*)d_in[6];
  const float* db1    = (const float*)d_in[7];
  const float* dw2    = (const float*)d_in[8];
  const float* db2    = (const float*)d_in[9];
  const float* gw1    = (const float*)d_in[10];
  const float* gb1    = (const float*)d_in[11];
  const float* gw2    = (const float*)d_in[12];
  const float* gb2    = (const float*)d_in[13];
  const float* wq     = (const float*)d_in[14];
  const float* wk     = (const float*)d_in[15];
  const float* wv     = (const float*)d_in[16];

  float* out = (float*)d_out;
  float* attn_pe = out + 131072;   // [65536][512] f32: holds pos_enc, overwritten in-place by attn

  char* w = (char*)d_ws;
  bf16_t* wqkvT  = (bf16_t*)w; w += (size_t)1536 * 512 * 2;
  bf16_t* dw2T   = (bf16_t*)w; w += (size_t)512 * 512 * 2;
  bf16_t* gw1T   = (bf16_t*)w; w += (size_t)512 * 512 * 2;
  bf16_t* gw2T   = (bf16_t*)w; w += (size_t)512 * 512 * 2;
  int*    knn    = (int*)w;    w += (size_t)65536 * 4;
  bf16_t* xb     = (bf16_t*)w; w += (size_t)4096 * 512 * 2;
  float*  qkv    = (float*)w;  w += (size_t)4096 * 1536 * 4;
  bf16_t* h12    = (bf16_t*)w; w += (size_t)65536 * 512 * 2;   // h1, then overwritten by h2
  float*  res_mid= (float*)w;  w += (size_t)4096 * 512 * 4;

  TC6 tc;
  tc.src[0] = wq;  tc.dst[0] = wqkvT;
  tc.src[1] = wk;  tc.dst[1] = wqkvT + 512 * 512;
  tc.src[2] = wv;  tc.dst[2] = wqkvT + 2 * 512 * 512;
  tc.src[3] = dw2; tc.dst[3] = dw2T;
  tc.src[4] = gw1; tc.dst[4] = gw1T;
  tc.src[5] = gw2; tc.dst[5] = gw2T;
  tcast6_kernel<<<6144, 256, 0, stream>>>(tc);

  knn_kernel<<<1024, 256, 0, stream>>>(xyz, knn);
  xfeat_kernel<<<4096, 256, 0, stream>>>(points, fc1_w, fc1_b, xb);

  // qkv = x @ [wq|wk|wv]  -> f32 [4096][1536]
  gemm_kernel<0, 0><<<dim3(12, 32), 256, 0, stream>>>(xb, wqkvT, qkv, nullptr, nullptr, 1536,
                                                      nullptr, nullptr, nullptr, nullptr);
  h1_kernel<<<4096, 256, 0, stream>>>(xyz, knn, dw1, db1, h12);

  // pos_enc = h1 @ delta_w2 + delta_b2 -> f32 into attn region of d_out
  gemm_kernel<0, 1><<<dim3(4, 512), 256, 0, stream>>>(h12, dw2T, attn_pe, nullptr, db2, 512,
                                                      nullptr, nullptr, nullptr, nullptr);

  // h2 = relu((q - k_gathered + pos_enc) @ gamma_w1 + gamma_b1) -> bf16 (overwrites h1)
  gemm_kernel<1, 2><<<dim3(4, 512), 256, 0, stream>>>(nullptr, gw1T, nullptr, h12, gb1, 512,
                                                      qkv, attn_pe, knn, nullptr);

  // a = h2 @ gamma_w2 + gamma_b2; attn = softmax(a/sqrt(512)) over k; res_mid = sum_k attn*(v+pe)
  gemm_kernel<0, 3><<<dim3(4, 512), 256, 0, stream>>>(h12, gw2T, nullptr, nullptr, gb2, 512,
                                                      qkv, attn_pe, knn, res_mid);

  final_kernel<<<512, 256, 0, stream>>>(res_mid, fc2_w, fc2_b, points, out);
}